// Round 18
// baseline (243.589 us; speedup 1.0000x reference)
//
#include <hip/hip_runtime.h>

typedef __attribute__((ext_vector_type(4))) float f32x4;
typedef __attribute__((ext_vector_type(4))) int   i32x4;
typedef __attribute__((ext_vector_type(8))) short short8;
typedef _Float16 half8 __attribute__((ext_vector_type(8)));

__device__ __forceinline__ unsigned short f2h(float f) {
  _Float16 h = (_Float16)f;                       // RTN
  return __builtin_bit_cast(unsigned short, h);
}
__device__ __forceinline__ float h2f(unsigned short u) {
  return (float)__builtin_bit_cast(_Float16, u);
}
__device__ __forceinline__ char q8(float v) {     // quantize at scale 24, clip +-127
  return (char)__float2int_rn(fminf(127.f, fmaxf(-127.f, v * 24.0f)));
}

// ---------------- unified cast: x (4096 blocks) + Wq/Wk/Wv (1024 blocks each) ----------------
__global__ __launch_bounds__(256) void cast_all(const float* __restrict__ x,
                                                const float* __restrict__ w0,
                                                const float* __restrict__ w1,
                                                const float* __restrict__ w2,
                                                unsigned short* __restrict__ xb,
                                                unsigned short* __restrict__ Wcat) {
  const int b = blockIdx.x;
  const float* src;
  unsigned short* dst;
  int i;
  if (b < 4096) {
    src = x; dst = xb; i = b * 256 + threadIdx.x;
  } else {
    const int wb  = b - 4096;
    const int seg = wb >> 10;
    src = (seg == 0) ? w0 : (seg == 1) ? w1 : w2;
    dst = Wcat + (size_t)seg * 1048576;
    i   = (wb & 1023) * 256 + threadIdx.x;
  }
  float4 v = ((const float4*)src)[i];
  ushort4 o;
  o.x = f2h(v.x); o.y = f2h(v.y); o.z = f2h(v.z); o.w = f2h(v.w);
  ((ushort4*)dst)[i] = o;
}

// ======================= 256x128 fat-wave NT GEMM (fp16) =======================
// Schedule per tile (stage-under-MFMA, single 48KB buffer):
//   read ALL frags (24 ds_read_b128) -> lgkmcnt(0) -> barrier
//   stage tile u+1 into the SAME buffer (gload_lds; lands during MFMA)
//   MFMA cluster (register-only; no LDS contention with own staging)
//   vmcnt(0) -> barrier
// Round-12's dbuf regression issued staging BEFORE the reads (LDS-pipe contention
// during the read phase); this is the inverse — staging overlaps only MFMA.
// MODE 0: ctx — all z write fp16 partials. MODE 2: QKV (i8 q|k + transposed vT).
template <int MODE>
__global__ __launch_bounds__(256, 2) void gemm8(
    const unsigned short* __restrict__ A, int lda,
    const unsigned short* __restrict__ B, int ldb,
    int ksplit, float alpha,
    float* __restrict__ C0, int ldc0,
    unsigned short* __restrict__ H1, int ldh1,
    unsigned short* __restrict__ H2, int ldh2,
    unsigned short* __restrict__ H3, int ldh3,
    unsigned short* __restrict__ Cqk, int ldqk,
    unsigned short* __restrict__ CvT, int ldvt) {
  __shared__ __attribute__((aligned(16))) unsigned short lds[24576];

  const int t    = threadIdx.x;
  const int lane = t & 63;
  const int wave = t >> 6;           // 0..3
  const int wr   = wave >> 1;        // 0..1  (M: 128-row half)
  const int wc   = wave & 1;         // 0..1  (N: 64-col half)

  const int nx   = gridDim.x;
  const int nwg  = nx * gridDim.y;
  const int orig = blockIdx.y * nx + blockIdx.x;
  const int wg   = (orig & 7) * (nwg >> 3) + (orig >> 3);
  const int bm   = (wg / nx) * 256;
  const int bn   = (wg % nx) * 128;

  const int kbeg = blockIdx.z * ksplit;
  const int NT   = ksplit >> 6;

  const unsigned short* gA = A + (size_t)bm * lda;
  const unsigned short* gB = B + (size_t)bn * ldb;

  auto stage = [&](const unsigned short* gbase, int ld, int k0, unsigned short* dst) {
#pragma unroll
    for (int j = 0; j < 4; ++j) {
      const int de = t * 8 + j * 2048;
      const int se = de ^ (((de >> 6) & 7) << 3);
      __builtin_amdgcn_global_load_lds(
          (const __attribute__((address_space(1))) void*)(gbase + (size_t)(se >> 6) * ld + k0 + (se & 63)),
          (__attribute__((address_space(3))) void*)(dst + de),
          16, 0, 0);
    }
  };

  f32x4 acc[8][4];
#pragma unroll
  for (int i = 0; i < 8; ++i)
#pragma unroll
    for (int j = 0; j < 4; ++j)
      acc[i][j] = (f32x4){0.f, 0.f, 0.f, 0.f};

  const int frow  = lane & 15;
  const int fk    = (lane >> 4) * 8;
  const int brow0 = wc * 64;

  // prologue: stage tile 0, drain, barrier
  stage(gA,                     lda, kbeg, lds);
  stage(gA + (size_t)128 * lda, lda, kbeg, lds + 8192);
  stage(gB,                     ldb, kbeg, lds + 16384);
  asm volatile("s_waitcnt vmcnt(0)" ::: "memory");
  __builtin_amdgcn_s_barrier();

  for (int u = 0; u < NT; ++u) {
    half8 bf[4][2], af[8][2];
#pragma unroll
    for (int n = 0; n < 4; ++n)
#pragma unroll
      for (int ks = 0; ks < 2; ++ks) {
        const int row = brow0 + n * 16 + frow;
        const int e = (row * 64 + ks * 32 + fk) ^ ((row & 7) << 3);
        bf[n][ks] = *(const half8*)(const void*)(lds + 16384 + e);
      }
#pragma unroll
    for (int m = 0; m < 8; ++m) {
      const int row = wr * 128 + m * 16 + frow;
      af[m][0] = *(const half8*)(const void*)(lds + ((row * 64 + fk) ^ ((row & 7) << 3)));
      af[m][1] = *(const half8*)(const void*)(lds + ((row * 64 + 32 + fk) ^ ((row & 7) << 3)));
    }
    asm volatile("s_waitcnt lgkmcnt(0)" ::: "memory");
    __builtin_amdgcn_s_barrier();          // all waves' reads retired -> buffer reusable

    if (u + 1 < NT) {
      const int k1 = kbeg + (u + 1) * 64;
      stage(gA,                     lda, k1, lds);
      stage(gA + (size_t)128 * lda, lda, k1, lds + 8192);
      stage(gB,                     ldb, k1, lds + 16384);
    }

#pragma unroll
    for (int m = 0; m < 8; ++m) {
#pragma unroll
      for (int n = 0; n < 4; ++n)
        acc[m][n] = __builtin_amdgcn_mfma_f32_16x16x32_f16(af[m][0], bf[n][0], acc[m][n], 0, 0, 0);
#pragma unroll
      for (int n = 0; n < 4; ++n)
        acc[m][n] = __builtin_amdgcn_mfma_f32_16x16x32_f16(af[m][1], bf[n][1], acc[m][n], 0, 0, 0);
    }
    asm volatile("s_waitcnt vmcnt(0)" ::: "memory");
    __builtin_amdgcn_s_barrier();          // tile u+1 visible to all waves
  }

  // ---- epilogue ----
  if constexpr (MODE == 0) {
    unsigned short* H; int ldh;
    if      (blockIdx.z == 0) { H = (unsigned short*)C0; ldh = ldc0; }
    else if (blockIdx.z == 1) { H = H1; ldh = ldh1; }
    else if (blockIdx.z == 2) { H = H2; ldh = ldh2; }
    else                      { H = H3; ldh = ldh3; }
#pragma unroll
    for (int m = 0; m < 8; ++m)
#pragma unroll
      for (int n = 0; n < 4; ++n) {
        const int row0 = bm + wr * 128 + m * 16 + (lane >> 4) * 4;
        const int col  = bn + wc * 64 + n * 16 + (lane & 15);
#pragma unroll
        for (int j = 0; j < 4; ++j)
          H[(size_t)(row0 + j) * ldh + col] = f2h(acc[m][n][j] * alpha);
      }
  } else {
    if (bn < 2048) {
      char* Q8 = (char*)Cqk;
#pragma unroll
      for (int m = 0; m < 8; ++m)
#pragma unroll
        for (int n = 0; n < 4; ++n) {
          const int row0 = bm + wr * 128 + m * 16 + (lane >> 4) * 4;
          const int col  = bn + wc * 64 + n * 16 + (lane & 15);
#pragma unroll
          for (int j = 0; j < 4; ++j)
            Q8[(size_t)(row0 + j) * ldqk + col] = q8(acc[m][n][j] * alpha);
        }
    } else {
      // vT via LDS transpose: two 128-row passes; T[cl][r] ushort, stride 136.
#pragma unroll
      for (int p = 0; p < 2; ++p) {
        __syncthreads();
        if (wr == p) {
#pragma unroll
          for (int m = 0; m < 8; ++m)
#pragma unroll
            for (int n = 0; n < 4; ++n) {
              const int cl = wc * 64 + n * 16 + (lane & 15);
              const int r  = m * 16 + (lane >> 4) * 4;
              ushort4 o;
              o.x = f2h(acc[m][n][0] * alpha);
              o.y = f2h(acc[m][n][1] * alpha);
              o.z = f2h(acc[m][n][2] * alpha);
              o.w = f2h(acc[m][n][3] * alpha);
              *(ushort4*)(lds + cl * 136 + r) = o;
            }
        }
        __syncthreads();
        const int cl = t >> 1, roff = (t & 1) * 64;
        const unsigned short* src = lds + cl * 136 + roff;
        unsigned short* dst = CvT + (size_t)(bn - 2048 + cl) * ldvt + bm + p * 128 + roff;
#pragma unroll
        for (int i = 0; i < 8; ++i)
          *(short8*)(dst + i * 8) = *(const short8*)(src + i * 8);
      }
    }
  }
}

// ======================= 256x128 fat-wave NT GEMM, i8 BK=128 (scores+exp) =======================
// Same stage-under-MFMA schedule.  P' = 512*exp(S-8) fp16 + Srow row-sum partials.
__global__ __launch_bounds__(256, 2) void gemm_i8(
    const char* __restrict__ Q, int ldq,    // [4096][ldq] i8
    const char* __restrict__ K, int ldk,
    float alpha,
    unsigned short* __restrict__ S, int lds_out,
    float* __restrict__ Srow) {
  __shared__ __attribute__((aligned(16))) char lds[49152];

  const int t    = threadIdx.x;
  const int lane = t & 63;
  const int wave = t >> 6;
  const int wr   = wave >> 1;
  const int wc   = wave & 1;

  const int nx   = gridDim.x;
  const int nwg  = nx * gridDim.y;
  const int orig = blockIdx.y * nx + blockIdx.x;
  const int wg   = (orig & 7) * (nwg >> 3) + (orig >> 3);
  const int bm   = (wg / nx) * 256;
  const int bn   = (wg % nx) * 128;

  const char* gA = Q + (size_t)bm * ldq;
  const char* gB = K + (size_t)bn * ldk;

  auto stage = [&](const char* gbase, int ld, int k0, char* dst, int nj) {
    for (int j = 0; j < nj; ++j) {
      const int de = t * 16 + j * 4096;
      const int se = de ^ (((de >> 7) & 7) << 4);      // pre-swizzled source byte
      __builtin_amdgcn_global_load_lds(
          (const __attribute__((address_space(1))) void*)(gbase + (size_t)(se >> 7) * ld + k0 + (se & 127)),
          (__attribute__((address_space(3))) void*)(dst + de),
          16, 0, 0);
    }
  };

  i32x4 acc[8][4];
#pragma unroll
  for (int i = 0; i < 8; ++i)
#pragma unroll
    for (int j = 0; j < 4; ++j)
      acc[i][j] = (i32x4){0, 0, 0, 0};

  const int frow = lane & 15;
  const int fkb  = (lane >> 4) * 16;
  const int brow0 = wc * 64;

  // prologue
  stage(gA, ldq, 0, lds, 8);
  stage(gB, ldk, 0, lds + 32768, 4);
  asm volatile("s_waitcnt vmcnt(0)" ::: "memory");
  __builtin_amdgcn_s_barrier();

  for (int u = 0; u < 8; ++u) {        // K = 1024 i8, BK = 128
    i32x4 bf[4][2], af[8][2];
#pragma unroll
    for (int n = 0; n < 4; ++n)
#pragma unroll
      for (int ks = 0; ks < 2; ++ks) {
        const int row = brow0 + n * 16 + frow;
        const int e = (row * 128 + ks * 64 + fkb) ^ ((row & 7) << 4);
        bf[n][ks] = *(const i32x4*)(const void*)(lds + 32768 + e);
      }
#pragma unroll
    for (int m = 0; m < 8; ++m) {
      const int row = wr * 128 + m * 16 + frow;
      af[m][0] = *(const i32x4*)(const void*)(lds + ((row * 128 + fkb) ^ ((row & 7) << 4)));
      af[m][1] = *(const i32x4*)(const void*)(lds + ((row * 128 + 64 + fkb) ^ ((row & 7) << 4)));
    }
    asm volatile("s_waitcnt lgkmcnt(0)" ::: "memory");
    __builtin_amdgcn_s_barrier();

    if (u + 1 < 8) {
      const int k1 = (u + 1) * 128;
      stage(gA, ldq, k1, lds, 8);
      stage(gB, ldk, k1, lds + 32768, 4);
    }

#pragma unroll
    for (int m = 0; m < 8; ++m) {
#pragma unroll
      for (int n = 0; n < 4; ++n)
        acc[m][n] = __builtin_amdgcn_mfma_i32_16x16x64_i8(af[m][0], bf[n][0], acc[m][n], 0, 0, 0);
#pragma unroll
      for (int n = 0; n < 4; ++n)
        acc[m][n] = __builtin_amdgcn_mfma_i32_16x16x64_i8(af[m][1], bf[n][1], acc[m][n], 0, 0, 0);
    }
    asm volatile("s_waitcnt vmcnt(0)" ::: "memory");
    __builtin_amdgcn_s_barrier();
  }

  // ---- epilogue: P' = 512*exp(S-8) fp16 + row-sum partials ----
  float rpart[8][4];
#pragma unroll
  for (int m = 0; m < 8; ++m)
#pragma unroll
    for (int j = 0; j < 4; ++j)
      rpart[m][j] = 0.f;

#pragma unroll
  for (int m = 0; m < 8; ++m)
#pragma unroll
    for (int n = 0; n < 4; ++n) {
      const int row0 = bm + wr * 128 + m * 16 + (lane >> 4) * 4;
      const int col  = bn + wc * 64 + n * 16 + (lane & 15);
#pragma unroll
      for (int j = 0; j < 4; ++j) {
        const float p = __expf((float)acc[m][n][j] * alpha - 1.7616798f); // 512*exp(S-8)
        S[(size_t)(row0 + j) * lds_out + col] = f2h(p);
        rpart[m][j] += p;
      }
    }
#pragma unroll
  for (int off = 1; off < 16; off <<= 1)
#pragma unroll
    for (int m = 0; m < 8; ++m)
#pragma unroll
      for (int j = 0; j < 4; ++j)
        rpart[m][j] += __shfl_xor(rpart[m][j], off);

  __syncthreads();                       // all LDS tile reads done; reuse as float[256]
  float* red = (float*)lds;
  if (wc == 0 && (lane & 15) == 0) {
#pragma unroll
    for (int m = 0; m < 8; ++m)
#pragma unroll
      for (int j = 0; j < 4; ++j)
        red[wr * 128 + m * 16 + (lane >> 4) * 4 + j] = rpart[m][j];
  }
  __syncthreads();
  if (wc == 1 && (lane & 15) == 0) {
#pragma unroll
    for (int m = 0; m < 8; ++m)
#pragma unroll
      for (int j = 0; j < 4; ++j)
        red[wr * 128 + m * 16 + (lane >> 4) * 4 + j] += rpart[m][j];
  }
  __syncthreads();
  Srow[(size_t)(bn >> 7) * 4096 + bm + t] = red[t];
}

// ---------------- combine split-K=4 fp16 partials; normalize by row sum ----------------
__global__ __launch_bounds__(256) void combine4(float* __restrict__ out,
                                                const unsigned short* __restrict__ p0,
                                                const unsigned short* __restrict__ p1,
                                                const unsigned short* __restrict__ p2,
                                                const unsigned short* __restrict__ p3,
                                                const float* __restrict__ Srow) {
  const int r = blockIdx.x, c = threadIdx.x;
  float s = 0.f;
#pragma unroll
  for (int i = 0; i < 32; ++i)
    s += Srow[(size_t)i * 4096 + r];
  const float inv = 1.0f / s;

  ushort4 a = ((const ushort4*)(p0 + (size_t)r * 8192))[c];
  ushort4 b = ((const ushort4*)(p1 + (size_t)r * 8192))[c];
  ushort4 d = ((const ushort4*)(p2 + (size_t)r * 8192))[c];
  ushort4 e = ((const ushort4*)(p3 + (size_t)r * 8192))[c];
  float4 o;
  o.x = (h2f(a.x) + h2f(b.x) + h2f(d.x) + h2f(e.x)) * inv;
  o.y = (h2f(a.y) + h2f(b.y) + h2f(d.y) + h2f(e.y)) * inv;
  o.z = (h2f(a.z) + h2f(b.z) + h2f(d.z) + h2f(e.z)) * inv;
  o.w = (h2f(a.w) + h2f(b.w) + h2f(d.w) + h2f(e.w)) * inv;
  ((float4*)(out + (size_t)r * 1024))[c] = o;
}

// ---------------- launch ----------------
extern "C" void kernel_launch(void* const* d_in, const int* in_sizes, int n_in,
                              void* d_out, int out_size, void* d_ws, size_t ws_size,
                              hipStream_t stream) {
  const float* x  = (const float*)d_in[0];
  const float* Wq = (const float*)d_in[1];
  const float* Wk = (const float*)d_in[2];
  const float* Wv = (const float*)d_in[3];

  // ws layout (bytes):
  //   [0, 64M)   : P' fp16, row r at [r*16K, r*16K+8K) (stride 8192 ushorts);
  //                ctx partials (fp16, ld 8192): z=2 at +8K, z=1 at +10K, z=3 at +12K, z=0 at +14K
  //   [64M, 72M) : QK i8 [4096][2048] (q|k, scale 24)
  //   [72M, ...) : Srow fp32 [32][4096]
  //   [80M, 88M) : vT fp16 [1024][4096]
  //   [88M, 96M) : xb fp16 [4096][1024]
  //   [96M,102M) : Wcat fp16 [3072][1024]
  char* ws = (char*)d_ws;
  unsigned short* Sh    = (unsigned short*)ws;                // fp16 P', row stride 8192
  unsigned short* Hp2   = (unsigned short*)(ws + 8192);       // fp16, ld 8192
  unsigned short* Hp1   = (unsigned short*)(ws + 10240);      // fp16, ld 8192
  unsigned short* Hp3   = (unsigned short*)(ws + 12288);      // fp16, ld 8192
  unsigned short* Hp0   = (unsigned short*)(ws + 14336);      // fp16, ld 8192
  char*           QK8   = (char*)(ws + 67108864);             // i8 [4096][2048]
  float*          Srow  = (float*)(ws + 75497472);            // [32][4096] fp32
  unsigned short* vT    = (unsigned short*)(ws + 83886080);   // [1024][4096]
  unsigned short* xb    = (unsigned short*)(ws + 92274688);
  unsigned short* Wcat  = (unsigned short*)(ws + 100663296);

  cast_all<<<7168, 256, 0, stream>>>(x, Wq, Wk, Wv, xb, Wcat);

  // fused QKV: q|k -> i8 QK8 (scale 24), v -> fp16 vT (transposed)
  gemm8<2><<<dim3(24, 16, 1), 256, 0, stream>>>(
      xb, 1024, Wcat, 1024, 1024, 1.0f,
      nullptr, 0, nullptr, 0, nullptr, 0, nullptr, 0,
      (unsigned short*)QK8, 2048, vT, 4096);

  // P' = 512*exp(S-8), S = (q@k^T)/32 in i8 (BK=128): alpha = 1/(24*24*32); + Srow partials
  gemm_i8<<<dim3(32, 16, 1), 256, 0, stream>>>(
      QK8, 2048, QK8 + 1024, 2048, 1.0f / 18432.0f, Sh, 8192, Srow);

  // context numerator O' = P' @ vT^T; split-K=4, all partials fp16 into S-row stripes
  gemm8<0><<<dim3(8, 16, 4), 256, 0, stream>>>(
      Sh, 8192, vT, 4096, 1024, 1.0f,
      (float*)Hp0, 8192, Hp1, 8192, Hp2, 8192, Hp3, 8192, nullptr, 0, nullptr, 0);
  // combine + softmax normalization
  combine4<<<4096, 256, 0, stream>>>((float*)d_out, Hp0, Hp1, Hp2, Hp3, Srow);
}

// Round 19
// 129.505 us; speedup vs baseline: 1.8809x; 1.8809x over previous
//
#include <hip/hip_runtime.h>

typedef __attribute__((ext_vector_type(4))) float f32x4;
typedef __attribute__((ext_vector_type(4))) int   i32x4;
typedef __attribute__((ext_vector_type(8))) short short8;
typedef _Float16 half8 __attribute__((ext_vector_type(8)));

__device__ __forceinline__ unsigned short f2h(float f) {
  _Float16 h = (_Float16)f;                       // RTN
  return __builtin_bit_cast(unsigned short, h);
}
__device__ __forceinline__ float h2f(unsigned short u) {
  return (float)__builtin_bit_cast(_Float16, u);
}
__device__ __forceinline__ char q8(float v) {     // quantize at scale 24, clip +-127
  return (char)__float2int_rn(fminf(127.f, fmaxf(-127.f, v * 24.0f)));
}

// ---------------- unified cast: x (4096 blocks) + Wq/Wk/Wv (1024 blocks each) ----------------
__global__ __launch_bounds__(256) void cast_all(const float* __restrict__ x,
                                                const float* __restrict__ w0,
                                                const float* __restrict__ w1,
                                                const float* __restrict__ w2,
                                                unsigned short* __restrict__ xb,
                                                unsigned short* __restrict__ Wcat) {
  const int b = blockIdx.x;
  const float* src;
  unsigned short* dst;
  int i;
  if (b < 4096) {
    src = x; dst = xb; i = b * 256 + threadIdx.x;
  } else {
    const int wb  = b - 4096;
    const int seg = wb >> 10;
    src = (seg == 0) ? w0 : (seg == 1) ? w1 : w2;
    dst = Wcat + (size_t)seg * 1048576;
    i   = (wb & 1023) * 256 + threadIdx.x;
  }
  float4 v = ((const float4*)src)[i];
  ushort4 o;
  o.x = f2h(v.x); o.y = f2h(v.y); o.z = f2h(v.z); o.w = f2h(v.w);
  ((ushort4*)dst)[i] = o;
}

// ======================= 256x128 fat-wave NT GEMM (fp16) =======================
// m97-style loop (stage -> vmcnt(0)+barrier -> frags+MFMA -> barrier); the 7
// schedule variants tried in rounds 3-18 (8-phase pinned/unpinned, lookahead,
// A-direct, B-early-dbuf, read-all-then-stage) were all neutral or regressions;
// this structure is the measured plateau (~3100 cyc/tile-pair, 1.38x max-pipe floor).
// MODE 0: ctx — all z write fp16 partials. MODE 2: QKV (i8 q|k + transposed vT).
template <int MODE>
__global__ __launch_bounds__(256, 2) void gemm8(
    const unsigned short* __restrict__ A, int lda,
    const unsigned short* __restrict__ B, int ldb,
    int ksplit, float alpha,
    float* __restrict__ C0, int ldc0,
    unsigned short* __restrict__ H1, int ldh1,
    unsigned short* __restrict__ H2, int ldh2,
    unsigned short* __restrict__ H3, int ldh3,
    unsigned short* __restrict__ Cqk, int ldqk,
    unsigned short* __restrict__ CvT, int ldvt) {
  __shared__ __attribute__((aligned(16))) unsigned short lds[24576];

  const int t    = threadIdx.x;
  const int lane = t & 63;
  const int wave = t >> 6;           // 0..3
  const int wr   = wave >> 1;        // 0..1  (M: 128-row half)
  const int wc   = wave & 1;         // 0..1  (N: 64-col half)

  const int nx   = gridDim.x;
  const int nwg  = nx * gridDim.y;
  const int orig = blockIdx.y * nx + blockIdx.x;
  const int wg   = (orig & 7) * (nwg >> 3) + (orig >> 3);
  const int bm   = (wg / nx) * 256;
  const int bn   = (wg % nx) * 128;

  const int kbeg = blockIdx.z * ksplit;
  const int NT   = ksplit >> 6;

  const unsigned short* gA = A + (size_t)bm * lda;
  const unsigned short* gB = B + (size_t)bn * ldb;

  auto stage = [&](const unsigned short* gbase, int ld, int k0, unsigned short* dst) {
#pragma unroll
    for (int j = 0; j < 4; ++j) {
      const int de = t * 8 + j * 2048;
      const int se = de ^ (((de >> 6) & 7) << 3);
      __builtin_amdgcn_global_load_lds(
          (const __attribute__((address_space(1))) void*)(gbase + (size_t)(se >> 6) * ld + k0 + (se & 63)),
          (__attribute__((address_space(3))) void*)(dst + de),
          16, 0, 0);
    }
  };

  f32x4 acc[8][4];
#pragma unroll
  for (int i = 0; i < 8; ++i)
#pragma unroll
    for (int j = 0; j < 4; ++j)
      acc[i][j] = (f32x4){0.f, 0.f, 0.f, 0.f};

  const int frow  = lane & 15;
  const int fk    = (lane >> 4) * 8;
  const int brow0 = wc * 64;

  for (int u = 0; u < NT; ++u) {
    const int k0 = kbeg + u * 64;
    stage(gA,                     lda, k0, lds);
    stage(gA + (size_t)128 * lda, lda, k0, lds + 8192);
    stage(gB,                     ldb, k0, lds + 16384);
    asm volatile("s_waitcnt vmcnt(0)" ::: "memory");
    __builtin_amdgcn_s_barrier();

    half8 bf[4][2];
#pragma unroll
    for (int n = 0; n < 4; ++n)
#pragma unroll
      for (int ks = 0; ks < 2; ++ks) {
        const int row = brow0 + n * 16 + frow;
        const int e = (row * 64 + ks * 32 + fk) ^ ((row & 7) << 3);
        bf[n][ks] = *(const half8*)(const void*)(lds + 16384 + e);
      }

#pragma unroll
    for (int m = 0; m < 8; ++m) {
      const int row = wr * 128 + m * 16 + frow;
      const half8 a0 = *(const half8*)(const void*)(lds + ((row * 64 + fk) ^ ((row & 7) << 3)));
      const half8 a1 = *(const half8*)(const void*)(lds + ((row * 64 + 32 + fk) ^ ((row & 7) << 3)));
#pragma unroll
      for (int n = 0; n < 4; ++n)
        acc[m][n] = __builtin_amdgcn_mfma_f32_16x16x32_f16(a0, bf[n][0], acc[m][n], 0, 0, 0);
#pragma unroll
      for (int n = 0; n < 4; ++n)
        acc[m][n] = __builtin_amdgcn_mfma_f32_16x16x32_f16(a1, bf[n][1], acc[m][n], 0, 0, 0);
    }
    __builtin_amdgcn_s_barrier();
  }

  // ---- epilogue ----
  if constexpr (MODE == 0) {
    unsigned short* H; int ldh;
    if      (blockIdx.z == 0) { H = (unsigned short*)C0; ldh = ldc0; }
    else if (blockIdx.z == 1) { H = H1; ldh = ldh1; }
    else if (blockIdx.z == 2) { H = H2; ldh = ldh2; }
    else                      { H = H3; ldh = ldh3; }
#pragma unroll
    for (int m = 0; m < 8; ++m)
#pragma unroll
      for (int n = 0; n < 4; ++n) {
        const int row0 = bm + wr * 128 + m * 16 + (lane >> 4) * 4;
        const int col  = bn + wc * 64 + n * 16 + (lane & 15);
#pragma unroll
        for (int j = 0; j < 4; ++j)
          H[(size_t)(row0 + j) * ldh + col] = f2h(acc[m][n][j] * alpha);
      }
  } else {
    if (bn < 2048) {
      char* Q8 = (char*)Cqk;
#pragma unroll
      for (int m = 0; m < 8; ++m)
#pragma unroll
        for (int n = 0; n < 4; ++n) {
          const int row0 = bm + wr * 128 + m * 16 + (lane >> 4) * 4;
          const int col  = bn + wc * 64 + n * 16 + (lane & 15);
#pragma unroll
          for (int j = 0; j < 4; ++j)
            Q8[(size_t)(row0 + j) * ldqk + col] = q8(acc[m][n][j] * alpha);
        }
    } else {
      // vT via LDS transpose: two 128-row passes; T[cl][r] ushort, stride 136.
#pragma unroll
      for (int p = 0; p < 2; ++p) {
        __syncthreads();
        if (wr == p) {
#pragma unroll
          for (int m = 0; m < 8; ++m)
#pragma unroll
            for (int n = 0; n < 4; ++n) {
              const int cl = wc * 64 + n * 16 + (lane & 15);
              const int r  = m * 16 + (lane >> 4) * 4;
              ushort4 o;
              o.x = f2h(acc[m][n][0] * alpha);
              o.y = f2h(acc[m][n][1] * alpha);
              o.z = f2h(acc[m][n][2] * alpha);
              o.w = f2h(acc[m][n][3] * alpha);
              *(ushort4*)(lds + cl * 136 + r) = o;
            }
        }
        __syncthreads();
        const int cl = t >> 1, roff = (t & 1) * 64;
        const unsigned short* src = lds + cl * 136 + roff;
        unsigned short* dst = CvT + (size_t)(bn - 2048 + cl) * ldvt + bm + p * 128 + roff;
#pragma unroll
        for (int i = 0; i < 8; ++i)
          *(short8*)(dst + i * 8) = *(const short8*)(src + i * 8);
      }
    }
  }
}

// ======================= 256x128 fat-wave NT GEMM, i8 BK=128 (scores+exp) =======================
// P'[m][n] = 512*exp(S - 8), S = alpha * sum_k Q8[m][k]*K8[n][k]; emits per-block
// row-sum partials Srow[bn>>7][bm + r] (shfl col-lane reduce + LDS wc-merge).
__global__ __launch_bounds__(256, 2) void gemm_i8(
    const char* __restrict__ Q, int ldq,    // [4096][ldq] i8
    const char* __restrict__ K, int ldk,
    float alpha,
    unsigned short* __restrict__ S, int lds_out,
    float* __restrict__ Srow) {
  __shared__ __attribute__((aligned(16))) char lds[49152];

  const int t    = threadIdx.x;
  const int lane = t & 63;
  const int wave = t >> 6;
  const int wr   = wave >> 1;
  const int wc   = wave & 1;

  const int nx   = gridDim.x;
  const int nwg  = nx * gridDim.y;
  const int orig = blockIdx.y * nx + blockIdx.x;
  const int wg   = (orig & 7) * (nwg >> 3) + (orig >> 3);
  const int bm   = (wg / nx) * 256;
  const int bn   = (wg % nx) * 128;

  const char* gA = Q + (size_t)bm * ldq;
  const char* gB = K + (size_t)bn * ldk;

  auto stage = [&](const char* gbase, int ld, int k0, char* dst, int nj) {
    for (int j = 0; j < nj; ++j) {
      const int de = t * 16 + j * 4096;
      const int se = de ^ (((de >> 7) & 7) << 4);      // pre-swizzled source byte
      __builtin_amdgcn_global_load_lds(
          (const __attribute__((address_space(1))) void*)(gbase + (size_t)(se >> 7) * ld + k0 + (se & 127)),
          (__attribute__((address_space(3))) void*)(dst + de),
          16, 0, 0);
    }
  };

  i32x4 acc[8][4];
#pragma unroll
  for (int i = 0; i < 8; ++i)
#pragma unroll
    for (int j = 0; j < 4; ++j)
      acc[i][j] = (i32x4){0, 0, 0, 0};

  const int frow = lane & 15;
  const int fkb  = (lane >> 4) * 16;
  const int brow0 = wc * 64;

  for (int u = 0; u < 8; ++u) {        // K = 1024 i8, BK = 128
    const int k0 = u * 128;
    stage(gA, ldq, k0, lds, 8);              // A: 256x128B = 32KB
    stage(gB, ldk, k0, lds + 32768, 4);      // B: 128x128B = 16KB
    asm volatile("s_waitcnt vmcnt(0)" ::: "memory");
    __builtin_amdgcn_s_barrier();

    i32x4 bf[4][2];
#pragma unroll
    for (int n = 0; n < 4; ++n)
#pragma unroll
      for (int ks = 0; ks < 2; ++ks) {
        const int row = brow0 + n * 16 + frow;
        const int e = (row * 128 + ks * 64 + fkb) ^ ((row & 7) << 4);
        bf[n][ks] = *(const i32x4*)(const void*)(lds + 32768 + e);
      }

#pragma unroll
    for (int m = 0; m < 8; ++m) {
      const int row = wr * 128 + m * 16 + frow;
      const i32x4 a0 = *(const i32x4*)(const void*)(lds + ((row * 128 + fkb) ^ ((row & 7) << 4)));
      const i32x4 a1 = *(const i32x4*)(const void*)(lds + ((row * 128 + 64 + fkb) ^ ((row & 7) << 4)));
#pragma unroll
      for (int n = 0; n < 4; ++n)
        acc[m][n] = __builtin_amdgcn_mfma_i32_16x16x64_i8(a0, bf[n][0], acc[m][n], 0, 0, 0);
#pragma unroll
      for (int n = 0; n < 4; ++n)
        acc[m][n] = __builtin_amdgcn_mfma_i32_16x16x64_i8(a1, bf[n][1], acc[m][n], 0, 0, 0);
    }
    __builtin_amdgcn_s_barrier();
  }

  // ---- epilogue: P' = 512*exp(S-8) fp16 + row-sum partials ----
  float rpart[8][4];
#pragma unroll
  for (int m = 0; m < 8; ++m)
#pragma unroll
    for (int j = 0; j < 4; ++j)
      rpart[m][j] = 0.f;

#pragma unroll
  for (int m = 0; m < 8; ++m)
#pragma unroll
    for (int n = 0; n < 4; ++n) {
      const int row0 = bm + wr * 128 + m * 16 + (lane >> 4) * 4;
      const int col  = bn + wc * 64 + n * 16 + (lane & 15);
#pragma unroll
      for (int j = 0; j < 4; ++j) {
        const float p = __expf((float)acc[m][n][j] * alpha - 1.7616798f); // 512*exp(S-8)
        S[(size_t)(row0 + j) * lds_out + col] = f2h(p);
        rpart[m][j] += p;
      }
    }
#pragma unroll
  for (int off = 1; off < 16; off <<= 1)
#pragma unroll
    for (int m = 0; m < 8; ++m)
#pragma unroll
      for (int j = 0; j < 4; ++j)
        rpart[m][j] += __shfl_xor(rpart[m][j], off);

  __syncthreads();                       // all LDS tile reads done; reuse as float[256]
  float* red = (float*)lds;
  if (wc == 0 && (lane & 15) == 0) {
#pragma unroll
    for (int m = 0; m < 8; ++m)
#pragma unroll
      for (int j = 0; j < 4; ++j)
        red[wr * 128 + m * 16 + (lane >> 4) * 4 + j] = rpart[m][j];
  }
  __syncthreads();
  if (wc == 1 && (lane & 15) == 0) {
#pragma unroll
    for (int m = 0; m < 8; ++m)
#pragma unroll
      for (int j = 0; j < 4; ++j)
        red[wr * 128 + m * 16 + (lane >> 4) * 4 + j] += rpart[m][j];
  }
  __syncthreads();
  Srow[(size_t)(bn >> 7) * 4096 + bm + t] = red[t];
}

// ---------------- combine split-K=4 fp16 partials; normalize by row sum ----------------
__global__ __launch_bounds__(256) void combine4(float* __restrict__ out,
                                                const unsigned short* __restrict__ p0,
                                                const unsigned short* __restrict__ p1,
                                                const unsigned short* __restrict__ p2,
                                                const unsigned short* __restrict__ p3,
                                                const float* __restrict__ Srow) {
  const int r = blockIdx.x, c = threadIdx.x;
  float s = 0.f;
#pragma unroll
  for (int i = 0; i < 32; ++i)
    s += Srow[(size_t)i * 4096 + r];
  const float inv = 1.0f / s;

  ushort4 a = ((const ushort4*)(p0 + (size_t)r * 8192))[c];
  ushort4 b = ((const ushort4*)(p1 + (size_t)r * 8192))[c];
  ushort4 d = ((const ushort4*)(p2 + (size_t)r * 8192))[c];
  ushort4 e = ((const ushort4*)(p3 + (size_t)r * 8192))[c];
  float4 o;
  o.x = (h2f(a.x) + h2f(b.x) + h2f(d.x) + h2f(e.x)) * inv;
  o.y = (h2f(a.y) + h2f(b.y) + h2f(d.y) + h2f(e.y)) * inv;
  o.z = (h2f(a.z) + h2f(b.z) + h2f(d.z) + h2f(e.z)) * inv;
  o.w = (h2f(a.w) + h2f(b.w) + h2f(d.w) + h2f(e.w)) * inv;
  ((float4*)(out + (size_t)r * 1024))[c] = o;
}

// ---------------- launch ----------------
extern "C" void kernel_launch(void* const* d_in, const int* in_sizes, int n_in,
                              void* d_out, int out_size, void* d_ws, size_t ws_size,
                              hipStream_t stream) {
  const float* x  = (const float*)d_in[0];
  const float* Wq = (const float*)d_in[1];
  const float* Wk = (const float*)d_in[2];
  const float* Wv = (const float*)d_in[3];

  // ws layout (bytes):
  //   [0, 64M)   : P' fp16, row r at [r*16K, r*16K+8K) (stride 8192 ushorts);
  //                ctx partials (fp16, ld 8192): z=2 at +8K, z=1 at +10K, z=3 at +12K, z=0 at +14K
  //   [64M, 72M) : QK i8 [4096][2048] (q|k, scale 24)
  //   [72M, ...) : Srow fp32 [32][4096]
  //   [80M, 88M) : vT fp16 [1024][4096]
  //   [88M, 96M) : xb fp16 [4096][1024]
  //   [96M,102M) : Wcat fp16 [3072][1024]
  char* ws = (char*)d_ws;
  unsigned short* Sh    = (unsigned short*)ws;                // fp16 P', row stride 8192
  unsigned short* Hp2   = (unsigned short*)(ws + 8192);       // fp16, ld 8192
  unsigned short* Hp1   = (unsigned short*)(ws + 10240);      // fp16, ld 8192
  unsigned short* Hp3   = (unsigned short*)(ws + 12288);      // fp16, ld 8192
  unsigned short* Hp0   = (unsigned short*)(ws + 14336);      // fp16, ld 8192
  char*           QK8   = (char*)(ws + 67108864);             // i8 [4096][2048]
  float*          Srow  = (float*)(ws + 75497472);            // [32][4096] fp32
  unsigned short* vT    = (unsigned short*)(ws + 83886080);   // [1024][4096]
  unsigned short* xb    = (unsigned short*)(ws + 92274688);
  unsigned short* Wcat  = (unsigned short*)(ws + 100663296);

  cast_all<<<7168, 256, 0, stream>>>(x, Wq, Wk, Wv, xb, Wcat);

  // fused QKV: q|k -> i8 QK8 (scale 24), v -> fp16 vT (transposed)
  gemm8<2><<<dim3(24, 16, 1), 256, 0, stream>>>(
      xb, 1024, Wcat, 1024, 1024, 1.0f,
      nullptr, 0, nullptr, 0, nullptr, 0, nullptr, 0,
      (unsigned short*)QK8, 2048, vT, 4096);

  // P' = 512*exp(S-8), S = (q@k^T)/32 in i8 (BK=128): alpha = 1/(24*24*32); + Srow partials
  gemm_i8<<<dim3(32, 16, 1), 256, 0, stream>>>(
      QK8, 2048, QK8 + 1024, 2048, 1.0f / 18432.0f, Sh, 8192, Srow);

  // context numerator O' = P' @ vT^T; split-K=4, all partials fp16 into S-row stripes
  gemm8<0><<<dim3(8, 16, 4), 256, 0, stream>>>(
      Sh, 8192, vT, 4096, 1024, 1.0f,
      (float*)Hp0, 8192, Hp1, 8192, Hp2, 8192, Hp3, 8192, nullptr, 0, nullptr, 0);
  // combine + softmax normalization
  combine4<<<4096, 256, 0, stream>>>((float*)d_out, Hp0, Hp1, Hp2, Hp3, Srow);
}